// Round 2
// baseline (586.323 us; speedup 1.0000x reference)
//
#include <hip/hip_runtime.h>
#include <hip/hip_bf16.h>

typedef __attribute__((ext_vector_type(8))) short short8;
typedef __attribute__((ext_vector_type(4))) float f32x4;

#define INF_C 1e10f
#define DM 1024
#define SL 2048
#define TL 2048
#define BATCH 8

__device__ __forceinline__ ushort f2bf(float f) {
  union { float f; unsigned u; } c; c.f = f;
  unsigned u = c.u;
  u += 0x7fffu + ((u >> 16) & 1u);
  return (ushort)(u >> 16);
}
__device__ __forceinline__ float bf2f(ushort h) {
  union { unsigned u; float f; } c; c.u = ((unsigned)h) << 16;
  return c.f;
}
__device__ __forceinline__ float wred_sum(float v) {
#pragma unroll
  for (int i = 32; i > 0; i >>= 1) v += __shfl_xor(v, i);
  return v;
}
__device__ __forceinline__ float wred_max(float v) {
#pragma unroll
  for (int i = 32; i > 0; i >>= 1) v = fmaxf(v, __shfl_xor(v, i));
  return v;
}

// ---------------- steps[b] = sum(mask_src)/sum(mask_trg) ----------------
__global__ __launch_bounds__(256) void steps_kernel(const float* __restrict__ ms,
                                                    const float* __restrict__ mt,
                                                    float* __restrict__ steps) {
  int b = blockIdx.x, tid = threadIdx.x;
  float ss = 0.f, ts = 0.f;
  for (int i = tid; i < SL; i += 256) ss += ms[b * SL + i];
  for (int i = tid; i < TL; i += 256) ts += mt[b * TL + i];
  ss = wred_sum(ss); ts = wred_sum(ts);
  __shared__ float s1[4], s2[4];
  int wid = tid >> 6, lane = tid & 63;
  if (lane == 0) { s1[wid] = ss; s2[wid] = ts; }
  __syncthreads();
  if (tid == 0)
    steps[b] = (s1[0] + s1[1] + s1[2] + s1[3]) / (s2[0] + s2[1] + s2[2] + s2[3]);
}

// ---------------- v[l] = sum_i wq_b[i] * wk_w[i,l] ----------------
__global__ __launch_bounds__(256) void v_kernel(const float* __restrict__ wk_w,
                                                const float* __restrict__ wq_b,
                                                float* __restrict__ v) {
  int j0 = blockIdx.x * 64;
  int ii = threadIdx.x >> 6;   // 0..3
  int jj = threadIdx.x & 63;
  float acc = 0.f;
  for (int i = ii; i < DM; i += 4)
    acc += wq_b[i] * wk_w[(long long)i * DM + j0 + jj];
  __shared__ float red[4][64];
  red[ii][jj] = acc;
  __syncthreads();
  if (ii == 0) v[j0 + jj] = red[0][jj] + red[1][jj] + red[2][jj] + red[3][jj];
}

// -------- key -> bf16 convert, fused with c[s] = key[s] . v --------
__global__ __launch_bounds__(256) void cvt_key_rowc(const float* __restrict__ key,
                                                    const float* __restrict__ v,
                                                    ushort* __restrict__ key_bf,
                                                    float* __restrict__ c_s) {
  int wid = threadIdx.x >> 6, lane = threadIdx.x & 63;
  int row = blockIdx.x * 4 + wid;  // 0..16383
  const float4* kr = (const float4*)(key + (long long)row * DM);
  const float4* v4 = (const float4*)v;
  ushort4* ob = (ushort4*)(key_bf + (long long)row * DM);
  float acc = 0.f;
#pragma unroll
  for (int i = 0; i < 4; i++) {
    int idx = i * 64 + lane;
    float4 x = kr[idx];
    float4 vv = v4[idx];
    acc += x.x * vv.x + x.y * vv.y + x.z * vv.z + x.w * vv.w;
    ushort4 o; o.x = f2bf(x.x); o.y = f2bf(x.y); o.z = f2bf(x.z); o.w = f2bf(x.w);
    ob[idx] = o;
  }
  acc = wred_sum(acc);
  if (lane == 0) c_s[row] = acc;
}

// -------- transposed bf16 copy of a 1024x1024 f32 matrix --------
__global__ __launch_bounds__(256) void cvtT(const float* __restrict__ wq_w,
                                            const float* __restrict__ wk_w,
                                            ushort* __restrict__ wqT,
                                            ushort* __restrict__ wkT) {
  const float* src = blockIdx.z ? wk_w : wq_w;
  ushort* dst = blockIdx.z ? wkT : wqT;
  __shared__ ushort t[64][68];
  int r = threadIdx.x >> 4;         // 0..15
  int c4 = (threadIdx.x & 15) * 4;  // 0..60
  int i0 = blockIdx.y * 64, j0 = blockIdx.x * 64;
#pragma unroll
  for (int rr = 0; rr < 4; rr++) {
    int i = rr * 16 + r;
    float4 x = *(const float4*)(src + (long long)(i0 + i) * DM + j0 + c4);
    t[c4 + 0][i] = f2bf(x.x); t[c4 + 1][i] = f2bf(x.y);
    t[c4 + 2][i] = f2bf(x.z); t[c4 + 3][i] = f2bf(x.w);
  }
  __syncthreads();
#pragma unroll
  for (int rr = 0; rr < 4; rr++) {
    int j = rr * 16 + r;
    ushort4 o;
    o.x = t[j][c4]; o.y = t[j][c4 + 1]; o.z = t[j][c4 + 2]; o.w = t[j][c4 + 3];
    *(ushort4*)(dst + (long long)(j0 + j) * DM + i0 + c4) = o;
  }
}

// ------------- per (b,t): l_att row stats, query, gate -------------
// one wave per row; 4 rows per block
__global__ __launch_bounds__(256) void query_kernel(
    const float* __restrict__ key, const float* __restrict__ mask_src,
    const float* __restrict__ gate_w, const float* __restrict__ gate_b,
    const float* __restrict__ steps, ushort* __restrict__ query_bf,
    float* __restrict__ mrow, float* __restrict__ zrow, float* __restrict__ gates) {
  int wid = threadIdx.x >> 6, lane = threadIdx.x & 63;
  int row = blockIdx.x * 4 + wid;
  int b = row >> 11, t = row & (TL - 1);
  float c = steps[b] * (float)t;
  const float* msk = mask_src + b * SL;
  float lmax = -3e38f;
  for (int s = lane; s < SL; s += 64) {
    float d = (float)s - c;
    float lg = -d * d * (1.f / 0.3f) - INF_C * (1.f - msk[s]);
    lmax = fmaxf(lmax, lg);
  }
  lmax = wred_max(lmax);
  float zs = 0.f;
  for (int s = lane; s < SL; s += 64) {
    float d = (float)s - c;
    float lg = -d * d * (1.f / 0.3f) - INF_C * (1.f - msk[s]);
    zs += __expf(lg - lmax);
  }
  zs = wred_sum(zs);
  // window accumulate: only s with weight > ~e^-35 contribute
  float R2 = 10.5f - 0.3f * lmax;
  float R = sqrtf(R2);
  int slo = max(0, (int)floorf(c - R));
  int shi = min(SL - 1, (int)ceilf(c + R));
  f32x4 qv[4];
#pragma unroll
  for (int i = 0; i < 4; i++) qv[i] = (f32x4){0.f, 0.f, 0.f, 0.f};
  const float* kb = key + (long long)b * SL * DM;
  for (int s = slo; s <= shi; ++s) {
    float d = (float)s - c;
    float lg = -d * d * (1.f / 0.3f) - INF_C * (1.f - msk[s]);
    float w = __expf(lg - lmax);
    if (w > 1e-20f) {
      const f32x4* kr = (const f32x4*)(kb + (long long)s * DM);
#pragma unroll
      for (int i = 0; i < 4; i++) qv[i] += w * kr[(i << 6) + lane];
    }
  }
  float invZ = 1.f / zs;
#pragma unroll
  for (int i = 0; i < 4; i++) qv[i] *= invZ;
  // gate = sigmoid(query . gate_w + gate_b)
  const f32x4* gw = (const f32x4*)gate_w;
  float gl = 0.f;
#pragma unroll
  for (int i = 0; i < 4; i++) {
    f32x4 g = gw[(i << 6) + lane];
    gl += qv[i].x * g.x + qv[i].y * g.y + qv[i].z * g.z + qv[i].w * g.w;
  }
  gl = wred_sum(gl);
  float gate = 1.f / (1.f + __expf(-(gl + gate_b[0])));
  ushort* qq = query_bf + (long long)row * DM;
#pragma unroll
  for (int i = 0; i < 4; i++) {
    ushort4 o;
    o.x = f2bf(qv[i].x); o.y = f2bf(qv[i].y); o.z = f2bf(qv[i].z); o.w = f2bf(qv[i].w);
    ((ushort4*)qq)[(i << 6) + lane] = o;
  }
  if (lane == 0) { mrow[row] = lmax; zrow[row] = zs; gates[row] = gate; }
}

// ---------------- bf16 GEMM: C[m,n] = sum_k A[m,k]*B[n,k] ----------------
// m97 structure: 128x128 tile, BK=32, 4 waves, global_load_lds width 16
typedef const __attribute__((address_space(1))) void* gp_t;
typedef __attribute__((address_space(3))) void* lp_t;
#define GLDS(g, l) __builtin_amdgcn_global_load_lds((gp_t)(g), (lp_t)(l), 16, 0, 0)

__global__ __launch_bounds__(256) void gemm_bt(
    const ushort* __restrict__ A, const ushort* __restrict__ Bm,
    ushort* __restrict__ Cout,
    int M, int N, int K, long long sA, long long sB, long long sC) {
  __shared__ ushort As[128 * 32];
  __shared__ ushort Bs[128 * 32];
  int z = blockIdx.z;
  const ushort* Ab = A + (long long)z * sA;
  const ushort* Bb = Bm + (long long)z * sB;
  int tid = threadIdx.x;
  int wid = tid >> 6, lane = tid & 63;
  int wr = wid >> 1, wc = wid & 1;
  int m0 = blockIdx.y * 128, n0 = blockIdx.x * 128;
  int srow = tid >> 2, scol = (tid & 3) * 8;
  const ushort* aSrc = Ab + (long long)(m0 + srow) * K + scol;
  const ushort* bSrc = Bb + (long long)(n0 + srow) * K + scol;
  ushort* AsW = As + (wid << 9);
  ushort* BsW = Bs + (wid << 9);
  const long long r64 = (long long)64 * K;
  f32x4 acc[4][4];
#pragma unroll
  for (int i = 0; i < 4; i++)
#pragma unroll
    for (int j = 0; j < 4; j++) acc[i][j] = (f32x4){0.f, 0.f, 0.f, 0.f};
  int fr = lane & 15, fg = lane >> 4;
  for (int k0 = 0; k0 < K; k0 += 32) {
    GLDS(aSrc, AsW);
    GLDS(aSrc + r64, AsW + 2048);
    GLDS(bSrc, BsW);
    GLDS(bSrc + r64, BsW + 2048);
    aSrc += 32; bSrc += 32;
    __syncthreads();
    short8 af[4], bfr[4];
#pragma unroll
    for (int mf = 0; mf < 4; mf++)
      af[mf] = *(const short8*)(As + ((wr * 64 + mf * 16 + fr) * 32 + fg * 8));
#pragma unroll
    for (int nf = 0; nf < 4; nf++)
      bfr[nf] = *(const short8*)(Bs + ((wc * 64 + nf * 16 + fr) * 32 + fg * 8));
#pragma unroll
    for (int mf = 0; mf < 4; mf++)
#pragma unroll
      for (int nf = 0; nf < 4; nf++)
        acc[mf][nf] = __builtin_amdgcn_mfma_f32_16x16x32_bf16(af[mf], bfr[nf], acc[mf][nf], 0, 0, 0);
    __syncthreads();
  }
  // epilogue: C row=(lane>>4)*4+j, col=lane&15 (verified layout)
#pragma unroll
  for (int mf = 0; mf < 4; mf++) {
#pragma unroll
    for (int nf = 0; nf < 4; nf++) {
      int col = n0 + wc * 64 + nf * 16 + fr;
      int rowb = m0 + wr * 64 + mf * 16 + fg * 4;
#pragma unroll
      for (int j = 0; j < 4; j++) {
        long long idx = (long long)z * sC + (long long)(rowb + j) * N + col;
        Cout[idx] = f2bf(acc[mf][nf][j]);
      }
    }
  }
}

// ------- final: row softmax of (dots + c[s]) + blend with l_att -------
__global__ __launch_bounds__(256) void final_kernel(
    const ushort* __restrict__ dots, const float* __restrict__ mask_src,
    const float* __restrict__ steps, const float* __restrict__ mrow,
    const float* __restrict__ zrow, const float* __restrict__ gates,
    const float* __restrict__ c_s, float* __restrict__ out) {
  int row = blockIdx.x;
  int b = row >> 11, t = row & (TL - 1);
  int tid = threadIdx.x;
  int wid = tid >> 6, lane = tid & 63;
  const ushort* dr = dots + (long long)row * SL;
  const float* msk = mask_src + b * SL;
  const float* csb = c_s + b * SL;
  ushort4 u0 = ((const ushort4*)dr)[tid * 2];
  ushort4 u1 = ((const ushort4*)dr)[tid * 2 + 1];
  float4 mk0 = ((const float4*)msk)[tid * 2];
  float4 mk1 = ((const float4*)msk)[tid * 2 + 1];
  float4 cs0 = ((const float4*)csb)[tid * 2];
  float4 cs1 = ((const float4*)csb)[tid * 2 + 1];
  float mk[8] = {mk0.x, mk0.y, mk0.z, mk0.w, mk1.x, mk1.y, mk1.z, mk1.w};
  float cs[8] = {cs0.x, cs0.y, cs0.z, cs0.w, cs1.x, cs1.y, cs1.z, cs1.w};
  float li[8];
  li[0] = bf2f(u0.x); li[1] = bf2f(u0.y); li[2] = bf2f(u0.z); li[3] = bf2f(u0.w);
  li[4] = bf2f(u1.x); li[5] = bf2f(u1.y); li[6] = bf2f(u1.z); li[7] = bf2f(u1.w);
  float lmax = -3e38f;
#pragma unroll
  for (int j = 0; j < 8; j++) {
    li[j] = (li[j] + cs[j] - (1.f - mk[j]) * INF_C) * (1.f / 32.f);
    lmax = fmaxf(lmax, li[j]);
  }
  __shared__ float sm[4], ss[4];
  lmax = wred_max(lmax);
  if (lane == 0) sm[wid] = lmax;
  __syncthreads();
  float m2 = fmaxf(fmaxf(sm[0], sm[1]), fmaxf(sm[2], sm[3]));
  float p[8], lsum = 0.f;
#pragma unroll
  for (int j = 0; j < 8; j++) { p[j] = __expf(li[j] - m2); lsum += p[j]; }
  lsum = wred_sum(lsum);
  if (lane == 0) ss[wid] = lsum;
  __syncthreads();
  float invZ2 = 1.f / (ss[0] + ss[1] + ss[2] + ss[3]);
  float c = steps[b] * (float)t;
  float m1 = mrow[row];
  float invZ1 = 1.f / zrow[row];
  float g = gates[row], omg = 1.f - g;
  float o[8];
#pragma unroll
  for (int j = 0; j < 8; j++) {
    int s = tid * 8 + j;
    float d = (float)s - c;
    float l1 = -d * d * (1.f / 0.3f) - (1.f - mk[j]) * INF_C;
    float la = __expf(l1 - m1) * invZ1;
    o[j] = omg * p[j] * invZ2 + g * la;
  }
  float4* op = (float4*)(out + (long long)row * SL);
  op[tid * 2] = (float4){o[0], o[1], o[2], o[3]};
  op[tid * 2 + 1] = (float4){o[4], o[5], o[6], o[7]};
}

extern "C" void kernel_launch(void* const* d_in, const int* in_sizes, int n_in,
                              void* d_out, int out_size, void* d_ws, size_t ws_size,
                              hipStream_t stream) {
  const float* key      = (const float*)d_in[0];
  const float* mask_src = (const float*)d_in[1];
  const float* mask_trg = (const float*)d_in[2];
  const float* wq_w     = (const float*)d_in[3];
  const float* wq_b     = (const float*)d_in[4];
  const float* wk_w     = (const float*)d_in[5];
  const float* wk_b     = (const float*)d_in[6];   // provably no effect (softmax shift invariance)
  const float* gate_w   = (const float*)d_in[7];
  const float* gate_b   = (const float*)d_in[8];
  float* out = (float*)d_out;
  (void)wk_b;

  // ws layout (elements)
  const long long nKD = (long long)BATCH * SL * DM;  // 16,777,216
  const long long nWW = (long long)DM * DM;          // 1,048,576
  const long long nTS = (long long)BATCH * TL * SL;  // 33,554,432
  ushort* key_bf   = (ushort*)d_ws;
  ushort* query_bf = key_bf + nKD;
  ushort* G_bf     = query_bf + nKD;
  ushort* wqT      = G_bf + nKD;
  ushort* wkT      = wqT + nWW;
  ushort* Wt       = wkT + nWW;
  ushort* dots     = Wt + nWW;
  float*  steps    = (float*)(dots + nTS);
  float*  mrow     = steps + 8;
  float*  zrow     = mrow + BATCH * TL;
  float*  gates    = zrow + BATCH * TL;
  float*  c_s      = gates + BATCH * TL;
  float*  vvec     = c_s + BATCH * SL;
  size_t needed = (size_t)((char*)(vvec + DM) - (char*)d_ws);
  if (ws_size < needed) return;

  steps_kernel<<<BATCH, 256, 0, stream>>>(mask_src, mask_trg, steps);
  v_kernel<<<16, 256, 0, stream>>>(wk_w, wq_b, vvec);
  cvt_key_rowc<<<BATCH * SL / 4, 256, 0, stream>>>(key, vvec, key_bf, c_s);
  cvtT<<<dim3(16, 16, 2), 256, 0, stream>>>(wq_w, wk_w, wqT, wkT);
  query_kernel<<<BATCH * TL / 4, 256, 0, stream>>>(key, mask_src, gate_w, gate_b,
                                                   steps, query_bf, mrow, zrow, gates);
  // Wt[l,j] = sum_i wk[i,l]*wq[i,j]  (= W^T, W = wq^T wk)
  gemm_bt<<<dim3(8, 8, 1), 256, 0, stream>>>(wkT, wqT, Wt, DM, DM, DM, 0, 0, 0);
  // G[t,l] = sum_j query[t,j] * Wt[l,j] = (query . W)[t,l]
  gemm_bt<<<dim3(8, 128, 1), 256, 0, stream>>>(query_bf, Wt, G_bf,
                                               BATCH * TL, DM, DM, 0, 0, 0);
  // dots[b,t,s] = sum_l G[b,t,l] * key[b,s,l]
  gemm_bt<<<dim3(16, 16, BATCH), 256, 0, stream>>>(
      G_bf, key_bf, dots, TL, SL, DM,
      (long long)TL * DM, (long long)SL * DM, (long long)TL * SL);
  final_kernel<<<BATCH * TL, 256, 0, stream>>>(dots, mask_src, steps, mrow, zrow,
                                               gates, c_s, out);
}

// Round 3
// 476.106 us; speedup vs baseline: 1.2315x; 1.2315x over previous
//
#include <hip/hip_runtime.h>
#include <hip/hip_bf16.h>

typedef __attribute__((ext_vector_type(8))) short short8;
typedef __attribute__((ext_vector_type(4))) float f32x4;

#define INF_C 1e10f
#define DM 1024
#define SL 2048
#define TL 2048
#define BATCH 8

__device__ __forceinline__ ushort f2bf(float f) {
  union { float f; unsigned u; } c; c.f = f;
  unsigned u = c.u;
  u += 0x7fffu + ((u >> 16) & 1u);
  return (ushort)(u >> 16);
}
__device__ __forceinline__ float bf2f(ushort h) {
  union { unsigned u; float f; } c; c.u = ((unsigned)h) << 16;
  return c.f;
}
__device__ __forceinline__ float wred_sum(float v) {
#pragma unroll
  for (int i = 32; i > 0; i >>= 1) v += __shfl_xor(v, i);
  return v;
}
__device__ __forceinline__ float wred_max(float v) {
#pragma unroll
  for (int i = 32; i > 0; i >>= 1) v = fmaxf(v, __shfl_xor(v, i));
  return v;
}

// ---------------- steps[b] = sum(mask_src)/sum(mask_trg) ----------------
__global__ __launch_bounds__(256) void steps_kernel(const float* __restrict__ ms,
                                                    const float* __restrict__ mt,
                                                    float* __restrict__ steps) {
  int b = blockIdx.x, tid = threadIdx.x;
  float ss = 0.f, ts = 0.f;
  for (int i = tid; i < SL; i += 256) ss += ms[b * SL + i];
  for (int i = tid; i < TL; i += 256) ts += mt[b * TL + i];
  ss = wred_sum(ss); ts = wred_sum(ts);
  __shared__ float s1[4], s2[4];
  int wid = tid >> 6, lane = tid & 63;
  if (lane == 0) { s1[wid] = ss; s2[wid] = ts; }
  __syncthreads();
  if (tid == 0)
    steps[b] = (s1[0] + s1[1] + s1[2] + s1[3]) / (s2[0] + s2[1] + s2[2] + s2[3]);
}

// ---- v[l] = sum_i wq_b[i] * wk_w[i,l]  (coalesced row-major + atomics) ----
// 64 blocks x 16 rows each; thread tid owns columns 4*tid..4*tid+3.
__global__ __launch_bounds__(256) void v_kernel(const float* __restrict__ wk_w,
                                                const float* __restrict__ wq_b,
                                                float* __restrict__ v) {
  int tid = threadIdx.x;
  int r0 = blockIdx.x * 16;
  float4 acc = {0.f, 0.f, 0.f, 0.f};
#pragma unroll
  for (int i = 0; i < 16; i++) {
    int row = r0 + i;
    float wb = wq_b[row];
    float4 x = ((const float4*)(wk_w + (long long)row * DM))[tid];
    acc.x += wb * x.x; acc.y += wb * x.y; acc.z += wb * x.z; acc.w += wb * x.w;
  }
  float* dst = v + tid * 4;
  atomicAdd(dst + 0, acc.x);
  atomicAdd(dst + 1, acc.y);
  atomicAdd(dst + 2, acc.z);
  atomicAdd(dst + 3, acc.w);
}

// -------- key -> bf16 convert, fused with c[s] = key[s] . v --------
__global__ __launch_bounds__(256) void cvt_key_rowc(const float* __restrict__ key,
                                                    const float* __restrict__ v,
                                                    ushort* __restrict__ key_bf,
                                                    float* __restrict__ c_s) {
  int wid = threadIdx.x >> 6, lane = threadIdx.x & 63;
  int row = blockIdx.x * 4 + wid;  // 0..16383
  const float4* kr = (const float4*)(key + (long long)row * DM);
  const float4* v4 = (const float4*)v;
  ushort4* ob = (ushort4*)(key_bf + (long long)row * DM);
  float acc = 0.f;
#pragma unroll
  for (int i = 0; i < 4; i++) {
    int idx = i * 64 + lane;
    float4 x = kr[idx];
    float4 vv = v4[idx];
    acc += x.x * vv.x + x.y * vv.y + x.z * vv.z + x.w * vv.w;
    ushort4 o; o.x = f2bf(x.x); o.y = f2bf(x.y); o.z = f2bf(x.z); o.w = f2bf(x.w);
    ob[idx] = o;
  }
  acc = wred_sum(acc);
  if (lane == 0) c_s[row] = acc;
}

// -------- transposed bf16 copy of a 1024x1024 f32 matrix --------
__global__ __launch_bounds__(256) void cvtT(const float* __restrict__ wq_w,
                                            const float* __restrict__ wk_w,
                                            ushort* __restrict__ wqT,
                                            ushort* __restrict__ wkT) {
  const float* src = blockIdx.z ? wk_w : wq_w;
  ushort* dst = blockIdx.z ? wkT : wqT;
  __shared__ ushort t[64][68];
  int r = threadIdx.x >> 4;         // 0..15
  int c4 = (threadIdx.x & 15) * 4;  // 0..60
  int i0 = blockIdx.y * 64, j0 = blockIdx.x * 64;
#pragma unroll
  for (int rr = 0; rr < 4; rr++) {
    int i = rr * 16 + r;
    float4 x = *(const float4*)(src + (long long)(i0 + i) * DM + j0 + c4);
    t[c4 + 0][i] = f2bf(x.x); t[c4 + 1][i] = f2bf(x.y);
    t[c4 + 2][i] = f2bf(x.z); t[c4 + 3][i] = f2bf(x.w);
  }
  __syncthreads();
#pragma unroll
  for (int rr = 0; rr < 4; rr++) {
    int j = rr * 16 + r;
    ushort4 o;
    o.x = t[j][c4]; o.y = t[j][c4 + 1]; o.z = t[j][c4 + 2]; o.w = t[j][c4 + 3];
    *(ushort4*)(dst + (long long)(j0 + j) * DM + i0 + c4) = o;
  }
}

// ------------- per (b,t): l_att row stats, query, gate -------------
__global__ __launch_bounds__(256) void query_kernel(
    const float* __restrict__ key, const float* __restrict__ mask_src,
    const float* __restrict__ gate_w, const float* __restrict__ gate_b,
    const float* __restrict__ steps, ushort* __restrict__ query_bf,
    float* __restrict__ mrow, float* __restrict__ zrow, float* __restrict__ gates) {
  int wid = threadIdx.x >> 6, lane = threadIdx.x & 63;
  int row = blockIdx.x * 4 + wid;
  int b = row >> 11, t = row & (TL - 1);
  float c = steps[b] * (float)t;
  const float* msk = mask_src + b * SL;
  float lmax = -3e38f;
  for (int s = lane; s < SL; s += 64) {
    float d = (float)s - c;
    float lg = -d * d * (1.f / 0.3f) - INF_C * (1.f - msk[s]);
    lmax = fmaxf(lmax, lg);
  }
  lmax = wred_max(lmax);
  float zs = 0.f;
  for (int s = lane; s < SL; s += 64) {
    float d = (float)s - c;
    float lg = -d * d * (1.f / 0.3f) - INF_C * (1.f - msk[s]);
    zs += __expf(lg - lmax);
  }
  zs = wred_sum(zs);
  // window accumulate: only s with weight > ~e^-35 contribute
  float R2 = 10.5f - 0.3f * lmax;
  float R = sqrtf(R2);
  int slo = max(0, (int)floorf(c - R));
  int shi = min(SL - 1, (int)ceilf(c + R));
  f32x4 qv[4];
#pragma unroll
  for (int i = 0; i < 4; i++) qv[i] = (f32x4){0.f, 0.f, 0.f, 0.f};
  const float* kb = key + (long long)b * SL * DM;
  for (int s = slo; s <= shi; ++s) {
    float d = (float)s - c;
    float lg = -d * d * (1.f / 0.3f) - INF_C * (1.f - msk[s]);
    float w = __expf(lg - lmax);
    if (w > 1e-20f) {
      const f32x4* kr = (const f32x4*)(kb + (long long)s * DM);
#pragma unroll
      for (int i = 0; i < 4; i++) qv[i] += w * kr[(i << 6) + lane];
    }
  }
  float invZ = 1.f / zs;
#pragma unroll
  for (int i = 0; i < 4; i++) qv[i] *= invZ;
  const f32x4* gw = (const f32x4*)gate_w;
  float gl = 0.f;
#pragma unroll
  for (int i = 0; i < 4; i++) {
    f32x4 g = gw[(i << 6) + lane];
    gl += qv[i].x * g.x + qv[i].y * g.y + qv[i].z * g.z + qv[i].w * g.w;
  }
  gl = wred_sum(gl);
  float gate = 1.f / (1.f + __expf(-(gl + gate_b[0])));
  ushort* qq = query_bf + (long long)row * DM;
#pragma unroll
  for (int i = 0; i < 4; i++) {
    ushort4 o;
    o.x = f2bf(qv[i].x); o.y = f2bf(qv[i].y); o.z = f2bf(qv[i].z); o.w = f2bf(qv[i].w);
    ((ushort4*)qq)[(i << 6) + lane] = o;
  }
  if (lane == 0) { mrow[row] = lmax; zrow[row] = zs; gates[row] = gate; }
}

// ---------------- bf16 GEMM: C[m,n] = sum_k A[m,k]*B[n,k] ----------------
// m97 structure: 128x128 tile, BK=32, 4 waves, global_load_lds width 16.
// MODE: XCD-chunked block swizzle (bijective, m204 pattern).
//   0: none (small grids / L2-resident)
//   1: grid must be (8,128): XCD c gets y' in [16c,16c+16), all x'
//   2: grid must be (16,16,8): XCD c gets batch z=c, 8x8 supertiles
typedef const __attribute__((address_space(1))) void* gp_t;
typedef __attribute__((address_space(3))) void* lp_t;
#define GLDS(g, l) __builtin_amdgcn_global_load_lds((gp_t)(g), (lp_t)(l), 16, 0, 0)

template <int MODE>
__global__ __launch_bounds__(256) void gemm_bt(
    const ushort* __restrict__ A, const ushort* __restrict__ Bm,
    ushort* __restrict__ Cout,
    int M, int N, int K, long long sA, long long sB, long long sC) {
  int bx = blockIdx.x, by = blockIdx.y, bz = blockIdx.z;
  if (MODE == 1) {
    int L = by * 8 + bx;
    int w = (L & 7) * 128 + (L >> 3);
    by = w >> 3; bx = w & 7;
  } else if (MODE == 2) {
    int L = (bz * 16 + by) * 16 + bx;
    int w = (L & 7) * 256 + (L >> 3);
    bz = w >> 8;
    int w8 = w & 255;
    int st = w8 >> 6, wi = w8 & 63;
    by = (st >> 1) * 8 + (wi >> 3);
    bx = (st & 1) * 8 + (wi & 7);
  }
  __shared__ ushort As[128 * 32];
  __shared__ ushort Bs[128 * 32];
  const ushort* Ab = A + (long long)bz * sA;
  const ushort* Bb = Bm + (long long)bz * sB;
  int tid = threadIdx.x;
  int wid = tid >> 6, lane = tid & 63;
  int wr = wid >> 1, wc = wid & 1;
  int m0 = by * 128, n0 = bx * 128;
  int srow = tid >> 2, scol = (tid & 3) * 8;
  const ushort* aSrc = Ab + (long long)(m0 + srow) * K + scol;
  const ushort* bSrc = Bb + (long long)(n0 + srow) * K + scol;
  ushort* AsW = As + (wid << 9);
  ushort* BsW = Bs + (wid << 9);
  const long long r64 = (long long)64 * K;
  f32x4 acc[4][4];
#pragma unroll
  for (int i = 0; i < 4; i++)
#pragma unroll
    for (int j = 0; j < 4; j++) acc[i][j] = (f32x4){0.f, 0.f, 0.f, 0.f};
  int fr = lane & 15, fg = lane >> 4;
  for (int k0 = 0; k0 < K; k0 += 32) {
    GLDS(aSrc, AsW);
    GLDS(aSrc + r64, AsW + 2048);
    GLDS(bSrc, BsW);
    GLDS(bSrc + r64, BsW + 2048);
    aSrc += 32; bSrc += 32;
    __syncthreads();
    short8 af[4], bfr[4];
#pragma unroll
    for (int mf = 0; mf < 4; mf++)
      af[mf] = *(const short8*)(As + ((wr * 64 + mf * 16 + fr) * 32 + fg * 8));
#pragma unroll
    for (int nf = 0; nf < 4; nf++)
      bfr[nf] = *(const short8*)(Bs + ((wc * 64 + nf * 16 + fr) * 32 + fg * 8));
#pragma unroll
    for (int mf = 0; mf < 4; mf++)
#pragma unroll
      for (int nf = 0; nf < 4; nf++)
        acc[mf][nf] = __builtin_amdgcn_mfma_f32_16x16x32_bf16(af[mf], bfr[nf], acc[mf][nf], 0, 0, 0);
    __syncthreads();
  }
  // epilogue: C row=(lane>>4)*4+j, col=lane&15 (verified layout)
#pragma unroll
  for (int mf = 0; mf < 4; mf++) {
#pragma unroll
    for (int nf = 0; nf < 4; nf++) {
      int col = n0 + wc * 64 + nf * 16 + fr;
      int rowb = m0 + wr * 64 + mf * 16 + fg * 4;
#pragma unroll
      for (int j = 0; j < 4; j++) {
        long long idx = (long long)bz * sC + (long long)(rowb + j) * N + col;
        Cout[idx] = f2bf(acc[mf][nf][j]);
      }
    }
  }
}

// ------- final: row softmax of (dots + c[s]) + blend with l_att -------
__global__ __launch_bounds__(256) void final_kernel(
    const ushort* __restrict__ dots, const float* __restrict__ mask_src,
    const float* __restrict__ steps, const float* __restrict__ mrow,
    const float* __restrict__ zrow, const float* __restrict__ gates,
    const float* __restrict__ c_s, float* __restrict__ out) {
  int row = blockIdx.x;
  int b = row >> 11, t = row & (TL - 1);
  int tid = threadIdx.x;
  int wid = tid >> 6, lane = tid & 63;
  const ushort* dr = dots + (long long)row * SL;
  const float* msk = mask_src + b * SL;
  const float* csb = c_s + b * SL;
  ushort4 u0 = ((const ushort4*)dr)[tid * 2];
  ushort4 u1 = ((const ushort4*)dr)[tid * 2 + 1];
  float4 mk0 = ((const float4*)msk)[tid * 2];
  float4 mk1 = ((const float4*)msk)[tid * 2 + 1];
  float4 cs0 = ((const float4*)csb)[tid * 2];
  float4 cs1 = ((const float4*)csb)[tid * 2 + 1];
  float mk[8] = {mk0.x, mk0.y, mk0.z, mk0.w, mk1.x, mk1.y, mk1.z, mk1.w};
  float cs[8] = {cs0.x, cs0.y, cs0.z, cs0.w, cs1.x, cs1.y, cs1.z, cs1.w};
  float li[8];
  li[0] = bf2f(u0.x); li[1] = bf2f(u0.y); li[2] = bf2f(u0.z); li[3] = bf2f(u0.w);
  li[4] = bf2f(u1.x); li[5] = bf2f(u1.y); li[6] = bf2f(u1.z); li[7] = bf2f(u1.w);
  float lmax = -3e38f;
#pragma unroll
  for (int j = 0; j < 8; j++) {
    li[j] = (li[j] + cs[j] - (1.f - mk[j]) * INF_C) * (1.f / 32.f);
    lmax = fmaxf(lmax, li[j]);
  }
  __shared__ float sm[4], ss[4];
  lmax = wred_max(lmax);
  if (lane == 0) sm[wid] = lmax;
  __syncthreads();
  float m2 = fmaxf(fmaxf(sm[0], sm[1]), fmaxf(sm[2], sm[3]));
  float p[8], lsum = 0.f;
#pragma unroll
  for (int j = 0; j < 8; j++) { p[j] = __expf(li[j] - m2); lsum += p[j]; }
  lsum = wred_sum(lsum);
  if (lane == 0) ss[wid] = lsum;
  __syncthreads();
  float invZ2 = 1.f / (ss[0] + ss[1] + ss[2] + ss[3]);
  float c = steps[b] * (float)t;
  float m1 = mrow[row];
  float invZ1 = 1.f / zrow[row];
  float g = gates[row], omg = 1.f - g;
  float o[8];
#pragma unroll
  for (int j = 0; j < 8; j++) {
    int s = tid * 8 + j;
    float d = (float)s - c;
    float l1 = -d * d * (1.f / 0.3f) - (1.f - mk[j]) * INF_C;
    float la = __expf(l1 - m1) * invZ1;
    o[j] = omg * p[j] * invZ2 + g * la;
  }
  float4* op = (float4*)(out + (long long)row * SL);
  op[tid * 2] = (float4){o[0], o[1], o[2], o[3]};
  op[tid * 2 + 1] = (float4){o[4], o[5], o[6], o[7]};
}

extern "C" void kernel_launch(void* const* d_in, const int* in_sizes, int n_in,
                              void* d_out, int out_size, void* d_ws, size_t ws_size,
                              hipStream_t stream) {
  const float* key      = (const float*)d_in[0];
  const float* mask_src = (const float*)d_in[1];
  const float* mask_trg = (const float*)d_in[2];
  const float* wq_w     = (const float*)d_in[3];
  const float* wq_b     = (const float*)d_in[4];
  const float* wk_w     = (const float*)d_in[5];
  const float* wk_b     = (const float*)d_in[6];   // provably no effect (softmax shift invariance)
  const float* gate_w   = (const float*)d_in[7];
  const float* gate_b   = (const float*)d_in[8];
  float* out = (float*)d_out;
  (void)wk_b;

  // ws layout (elements)
  const long long nKD = (long long)BATCH * SL * DM;  // 16,777,216
  const long long nWW = (long long)DM * DM;          // 1,048,576
  const long long nTS = (long long)BATCH * TL * SL;  // 33,554,432
  ushort* key_bf   = (ushort*)d_ws;
  ushort* query_bf = key_bf + nKD;
  ushort* G_bf     = query_bf + nKD;
  ushort* wqT      = G_bf + nKD;
  ushort* wkT      = wqT + nWW;
  ushort* Wt       = wkT + nWW;
  ushort* dots     = Wt + nWW;
  float*  steps    = (float*)(dots + nTS);
  float*  mrow     = steps + 8;
  float*  zrow     = mrow + BATCH * TL;
  float*  gates    = zrow + BATCH * TL;
  float*  c_s      = gates + BATCH * TL;
  float*  vvec     = c_s + BATCH * SL;
  size_t needed = (size_t)((char*)(vvec + DM) - (char*)d_ws);
  if (ws_size < needed) return;

  steps_kernel<<<BATCH, 256, 0, stream>>>(mask_src, mask_trg, steps);
  hipMemsetAsync(vvec, 0, DM * sizeof(float), stream);
  v_kernel<<<64, 256, 0, stream>>>(wk_w, wq_b, vvec);
  cvt_key_rowc<<<BATCH * SL / 4, 256, 0, stream>>>(key, vvec, key_bf, c_s);
  cvtT<<<dim3(16, 16, 2), 256, 0, stream>>>(wq_w, wk_w, wqT, wkT);
  query_kernel<<<BATCH * TL / 4, 256, 0, stream>>>(key, mask_src, gate_w, gate_b,
                                                   steps, query_bf, mrow, zrow, gates);
  // Wt[l,j] = sum_i wk[i,l]*wq[i,j]  (= W^T, W = wq^T wk)
  gemm_bt<0><<<dim3(8, 8, 1), 256, 0, stream>>>(wkT, wqT, Wt, DM, DM, DM, 0, 0, 0);
  // G[t,l] = sum_j query[t,j] * Wt[l,j] = (query . W)[t,l]
  gemm_bt<1><<<dim3(8, 128, 1), 256, 0, stream>>>(query_bf, Wt, G_bf,
                                                  BATCH * TL, DM, DM, 0, 0, 0);
  // dots[b,t,s] = sum_l G[b,t,l] * key[b,s,l]
  gemm_bt<2><<<dim3(16, 16, BATCH), 256, 0, stream>>>(
      G_bf, key_bf, dots, TL, SL, DM,
      (long long)TL * DM, (long long)SL * DM, (long long)TL * SL);
  final_kernel<<<BATCH * TL, 256, 0, stream>>>(dots, mask_src, steps, mrow, zrow,
                                               gates, c_s, out);
}

// Round 4
// 440.486 us; speedup vs baseline: 1.3311x; 1.0809x over previous
//
#include <hip/hip_runtime.h>
#include <hip/hip_bf16.h>

typedef __attribute__((ext_vector_type(8))) short short8;
typedef __attribute__((ext_vector_type(4))) float f32x4;

#define INF_C 1e10f
#define DM 1024
#define SL 2048
#define TL 2048
#define BATCH 8

__device__ __forceinline__ ushort f2bf(float f) {
  union { float f; unsigned u; } c; c.f = f;
  unsigned u = c.u;
  u += 0x7fffu + ((u >> 16) & 1u);
  return (ushort)(u >> 16);
}
__device__ __forceinline__ float bf2f(ushort h) {
  union { unsigned u; float f; } c; c.u = ((unsigned)h) << 16;
  return c.f;
}
__device__ __forceinline__ float wred_sum(float v) {
#pragma unroll
  for (int i = 32; i > 0; i >>= 1) v += __shfl_xor(v, i);
  return v;
}
__device__ __forceinline__ float wred_max(float v) {
#pragma unroll
  for (int i = 32; i > 0; i >>= 1) v = fmaxf(v, __shfl_xor(v, i));
  return v;
}

// ---------------- steps[b] = sum(mask_src)/sum(mask_trg) ----------------
__global__ __launch_bounds__(256) void steps_kernel(const float* __restrict__ ms,
                                                    const float* __restrict__ mt,
                                                    float* __restrict__ steps) {
  int b = blockIdx.x, tid = threadIdx.x;
  float ss = 0.f, ts = 0.f;
  for (int i = tid; i < SL; i += 256) ss += ms[b * SL + i];
  for (int i = tid; i < TL; i += 256) ts += mt[b * TL + i];
  ss = wred_sum(ss); ts = wred_sum(ts);
  __shared__ float s1[4], s2[4];
  int wid = tid >> 6, lane = tid & 63;
  if (lane == 0) { s1[wid] = ss; s2[wid] = ts; }
  __syncthreads();
  if (tid == 0)
    steps[b] = (s1[0] + s1[1] + s1[2] + s1[3]) / (s2[0] + s2[1] + s2[2] + s2[3]);
}

// ---- v[l] = sum_i wq_b[i] * wk_w[i,l]  (coalesced row-major + atomics) ----
__global__ __launch_bounds__(256) void v_kernel(const float* __restrict__ wk_w,
                                                const float* __restrict__ wq_b,
                                                float* __restrict__ v) {
  int tid = threadIdx.x;
  int r0 = blockIdx.x * 16;
  float4 acc = {0.f, 0.f, 0.f, 0.f};
#pragma unroll
  for (int i = 0; i < 16; i++) {
    int row = r0 + i;
    float wb = wq_b[row];
    float4 x = ((const float4*)(wk_w + (long long)row * DM))[tid];
    acc.x += wb * x.x; acc.y += wb * x.y; acc.z += wb * x.z; acc.w += wb * x.w;
  }
  float* dst = v + tid * 4;
  atomicAdd(dst + 0, acc.x);
  atomicAdd(dst + 1, acc.y);
  atomicAdd(dst + 2, acc.z);
  atomicAdd(dst + 3, acc.w);
}

// -------- key -> bf16 convert, fused with c[s] = key[s] . v --------
__global__ __launch_bounds__(256) void cvt_key_rowc(const float* __restrict__ key,
                                                    const float* __restrict__ v,
                                                    ushort* __restrict__ key_bf,
                                                    float* __restrict__ c_s) {
  int wid = threadIdx.x >> 6, lane = threadIdx.x & 63;
  int row = blockIdx.x * 4 + wid;  // 0..16383
  const float4* kr = (const float4*)(key + (long long)row * DM);
  const float4* v4 = (const float4*)v;
  ushort4* ob = (ushort4*)(key_bf + (long long)row * DM);
  float acc = 0.f;
#pragma unroll
  for (int i = 0; i < 4; i++) {
    int idx = i * 64 + lane;
    float4 x = kr[idx];
    float4 vv = v4[idx];
    acc += x.x * vv.x + x.y * vv.y + x.z * vv.z + x.w * vv.w;
    ushort4 o; o.x = f2bf(x.x); o.y = f2bf(x.y); o.z = f2bf(x.z); o.w = f2bf(x.w);
    ob[idx] = o;
  }
  acc = wred_sum(acc);
  if (lane == 0) c_s[row] = acc;
}

// -------- transposed bf16 copy of a 1024x1024 f32 matrix --------
__global__ __launch_bounds__(256) void cvtT(const float* __restrict__ wq_w,
                                            const float* __restrict__ wk_w,
                                            ushort* __restrict__ wqT,
                                            ushort* __restrict__ wkT) {
  const float* src = blockIdx.z ? wk_w : wq_w;
  ushort* dst = blockIdx.z ? wkT : wqT;
  __shared__ ushort t[64][68];
  int r = threadIdx.x >> 4;         // 0..15
  int c4 = (threadIdx.x & 15) * 4;  // 0..60
  int i0 = blockIdx.y * 64, j0 = blockIdx.x * 64;
#pragma unroll
  for (int rr = 0; rr < 4; rr++) {
    int i = rr * 16 + r;
    float4 x = *(const float4*)(src + (long long)(i0 + i) * DM + j0 + c4);
    t[c4 + 0][i] = f2bf(x.x); t[c4 + 1][i] = f2bf(x.y);
    t[c4 + 2][i] = f2bf(x.z); t[c4 + 3][i] = f2bf(x.w);
  }
  __syncthreads();
#pragma unroll
  for (int rr = 0; rr < 4; rr++) {
    int j = rr * 16 + r;
    ushort4 o;
    o.x = t[j][c4]; o.y = t[j][c4 + 1]; o.z = t[j][c4 + 2]; o.w = t[j][c4 + 3];
    *(ushort4*)(dst + (long long)(j0 + j) * DM + i0 + c4) = o;
  }
}

// ------------- per (b,t): l_att row stats, query, gate -------------
__global__ __launch_bounds__(256) void query_kernel(
    const float* __restrict__ key, const float* __restrict__ mask_src,
    const float* __restrict__ gate_w, const float* __restrict__ gate_b,
    const float* __restrict__ steps, ushort* __restrict__ query_bf,
    float* __restrict__ mrow, float* __restrict__ zrow, float* __restrict__ gates) {
  int wid = threadIdx.x >> 6, lane = threadIdx.x & 63;
  int row = blockIdx.x * 4 + wid;
  int b = row >> 11, t = row & (TL - 1);
  float c = steps[b] * (float)t;
  const float* msk = mask_src + b * SL;
  float lmax = -3e38f;
  for (int s = lane; s < SL; s += 64) {
    float d = (float)s - c;
    float lg = -d * d * (1.f / 0.3f) - INF_C * (1.f - msk[s]);
    lmax = fmaxf(lmax, lg);
  }
  lmax = wred_max(lmax);
  float zs = 0.f;
  for (int s = lane; s < SL; s += 64) {
    float d = (float)s - c;
    float lg = -d * d * (1.f / 0.3f) - INF_C * (1.f - msk[s]);
    zs += __expf(lg - lmax);
  }
  zs = wred_sum(zs);
  // window accumulate: only s with weight > ~e^-35 contribute
  float R2 = 10.5f - 0.3f * lmax;
  float R = sqrtf(R2);
  int slo = max(0, (int)floorf(c - R));
  int shi = min(SL - 1, (int)ceilf(c + R));
  f32x4 qv[4];
#pragma unroll
  for (int i = 0; i < 4; i++) qv[i] = (f32x4){0.f, 0.f, 0.f, 0.f};
  const float* kb = key + (long long)b * SL * DM;
  for (int s = slo; s <= shi; ++s) {
    float d = (float)s - c;
    float lg = -d * d * (1.f / 0.3f) - INF_C * (1.f - msk[s]);
    float w = __expf(lg - lmax);
    if (w > 1e-20f) {
      const f32x4* kr = (const f32x4*)(kb + (long long)s * DM);
#pragma unroll
      for (int i = 0; i < 4; i++) qv[i] += w * kr[(i << 6) + lane];
    }
  }
  float invZ = 1.f / zs;
#pragma unroll
  for (int i = 0; i < 4; i++) qv[i] *= invZ;
  const f32x4* gw = (const f32x4*)gate_w;
  float gl = 0.f;
#pragma unroll
  for (int i = 0; i < 4; i++) {
    f32x4 g = gw[(i << 6) + lane];
    gl += qv[i].x * g.x + qv[i].y * g.y + qv[i].z * g.z + qv[i].w * g.w;
  }
  gl = wred_sum(gl);
  float gate = 1.f / (1.f + __expf(-(gl + gate_b[0])));
  ushort* qq = query_bf + (long long)row * DM;
#pragma unroll
  for (int i = 0; i < 4; i++) {
    ushort4 o;
    o.x = f2bf(qv[i].x); o.y = f2bf(qv[i].y); o.z = f2bf(qv[i].z); o.w = f2bf(qv[i].w);
    ((ushort4*)qq)[(i << 6) + lane] = o;
  }
  if (lane == 0) { mrow[row] = lmax; zrow[row] = zs; gates[row] = gate; }
}

typedef const __attribute__((address_space(1))) void* gp_t;
typedef __attribute__((address_space(3))) void* lp_t;
#define GLDS(g, l) __builtin_amdgcn_global_load_lds((gp_t)(g), (lp_t)(l), 16, 0, 0)
#define WAITVM8 asm volatile("s_waitcnt vmcnt(8)" ::: "memory")
#define WAITVM4 asm volatile("s_waitcnt vmcnt(4)" ::: "memory")
#define WAITVM0 asm volatile("s_waitcnt vmcnt(0)" ::: "memory")
#define MFMA_BF16 __builtin_amdgcn_mfma_f32_16x16x32_bf16

// ---- small-matrix GEMM (m97 structure), kept for Wt (1024x1024x1024) ----
__global__ __launch_bounds__(256) void gemm_bt(
    const ushort* __restrict__ A, const ushort* __restrict__ Bm,
    ushort* __restrict__ Cout,
    int M, int N, int K, long long sA, long long sB, long long sC) {
  __shared__ ushort As[128 * 32];
  __shared__ ushort Bs[128 * 32];
  int z = blockIdx.z;
  const ushort* Ab = A + (long long)z * sA;
  const ushort* Bb = Bm + (long long)z * sB;
  int tid = threadIdx.x;
  int wid = tid >> 6, lane = tid & 63;
  int wr = wid >> 1, wc = wid & 1;
  int m0 = blockIdx.y * 128, n0 = blockIdx.x * 128;
  int srow = tid >> 2, scol = (tid & 3) * 8;
  const ushort* aSrc = Ab + (long long)(m0 + srow) * K + scol;
  const ushort* bSrc = Bb + (long long)(n0 + srow) * K + scol;
  ushort* AsW = As + (wid << 9);
  ushort* BsW = Bs + (wid << 9);
  const long long r64 = (long long)64 * K;
  f32x4 acc[4][4];
#pragma unroll
  for (int i = 0; i < 4; i++)
#pragma unroll
    for (int j = 0; j < 4; j++) acc[i][j] = (f32x4){0.f, 0.f, 0.f, 0.f};
  int fr = lane & 15, fg = lane >> 4;
  for (int k0 = 0; k0 < K; k0 += 32) {
    GLDS(aSrc, AsW);
    GLDS(aSrc + r64, AsW + 2048);
    GLDS(bSrc, BsW);
    GLDS(bSrc + r64, BsW + 2048);
    aSrc += 32; bSrc += 32;
    __syncthreads();
    short8 af[4], bfr[4];
#pragma unroll
    for (int mf = 0; mf < 4; mf++)
      af[mf] = *(const short8*)(As + ((wr * 64 + mf * 16 + fr) * 32 + fg * 8));
#pragma unroll
    for (int nf = 0; nf < 4; nf++)
      bfr[nf] = *(const short8*)(Bs + ((wc * 64 + nf * 16 + fr) * 32 + fg * 8));
#pragma unroll
    for (int mf = 0; mf < 4; mf++)
#pragma unroll
      for (int nf = 0; nf < 4; nf++)
        acc[mf][nf] = MFMA_BF16(af[mf], bfr[nf], acc[mf][nf], 0, 0, 0);
    __syncthreads();
  }
#pragma unroll
  for (int mf = 0; mf < 4; mf++) {
#pragma unroll
    for (int nf = 0; nf < 4; nf++) {
      int col = n0 + wc * 64 + nf * 16 + fr;
      int rowb = m0 + wr * 64 + mf * 16 + fg * 4;
#pragma unroll
      for (int j = 0; j < 4; j++) {
        long long idx = (long long)z * sC + (long long)(rowb + j) * N + col;
        Cout[idx] = f2bf(acc[mf][nf][j]);
      }
    }
  }
}

// ---- 256x256 deep-pipelined GEMM: C[m,n] = sum_k A[m,k]*B[n,k], bf16 out ----
// BK=32, 8 waves (2x4), 4 LDS K-tile buffers (128 KB), tile t+3 staged during
// iter t, counted vmcnt(8) at iter end (never 0 in steady state), raw
// s_barrier + setprio phases (T3+T4+T5). SWZ: 1 = grid(4,64) XCD y-chunks;
// 2 = grid(8,8,8) batch-per-XCD + 4x4 supertiles.
template <int SWZ>
__global__ __launch_bounds__(512, 2) void gemm256(
    const ushort* __restrict__ A, const ushort* __restrict__ Bm,
    ushort* __restrict__ Cout, int N, int K,
    long long sA, long long sB, long long sC) {
  extern __shared__ ushort lds[];  // 4 * 16384 ushorts = 128 KB
  int bx = blockIdx.x, by = blockIdx.y, bz = blockIdx.z;
  if (SWZ == 1) {
    int L = by * 4 + bx;              // 0..255, XCD = L%8
    int w = (L & 7) * 32 + (L >> 3);  // XCD c owns w in [32c, 32c+32)
    by = w >> 2; bx = w & 3;
  } else if (SWZ == 2) {
    int L = (bz * 8 + by) * 8 + bx;   // 0..511
    int w = (L & 7) * 64 + (L >> 3);  // XCD c owns one batch
    bz = w >> 6;
    int w6 = w & 63;
    int st = w6 >> 4, wi = w6 & 15;   // 4x4 supertiles (L2 blocking)
    by = (st >> 1) * 4 + (wi >> 2);
    bx = (st & 1) * 4 + (wi & 3);
  }
  const ushort* Ab = A + (long long)bz * sA;
  const ushort* Bb = Bm + (long long)bz * sB;
  int tid = threadIdx.x;
  int wid = tid >> 6, lane = tid & 63;
  int wr = wid >> 2, wc = wid & 3;     // 2 x 4 wave grid
  int m0 = by * 256, n0 = bx * 256;
  int fr = lane & 15, fg = lane >> 4;
  int srow = tid >> 2, scol = (tid & 3) * 8;
  const ushort* aS = Ab + (long long)(m0 + srow) * K + scol;
  const ushort* bS = Bb + (long long)(n0 + srow) * K + scol;
  const long long r128 = (long long)128 * K;
  int nt = K >> 5;
  f32x4 acc[8][4];
#pragma unroll
  for (int i = 0; i < 8; i++)
#pragma unroll
    for (int j = 0; j < 4; j++) acc[i][j] = (f32x4){0.f, 0.f, 0.f, 0.f};
  // prologue: stage tiles 0,1,2 (12 GLDS calls outstanding)
#pragma unroll
  for (int tt = 0; tt < 3; tt++) {
    ushort* d = lds + tt * 16384 + (wid << 9);
    const ushort* ga = aS + tt * 32;
    const ushort* gb = bS + tt * 32;
    GLDS(ga, d);            GLDS(ga + r128, d + 4096);
    GLDS(gb, d + 8192);     GLDS(gb + r128, d + 12288);
  }
  WAITVM8;  // tile 0 landed (8 younger = tiles 1,2 stay in flight)
  __builtin_amdgcn_s_barrier();
  const int aO = (wr * 128 + fr) * 32 + fg * 8;
  const int bO = 8192 + (wc * 64 + fr) * 32 + fg * 8;
  for (int t = 0; t < nt; ++t) {
    const ushort* buf = lds + (t & 3) * 16384;
    ushort* dst = lds + ((t + 3) & 3) * 16384 + (wid << 9);  // == buf[(t-1)&3]: reads done
    const ushort* ga = aS + (long long)(t + 3) * 32;
    const ushort* gb = bS + (long long)(t + 3) * 32;
    bool doSt = (t + 3 < nt);
    short8 aF[8], bF[4];
    // ---- phase 0: read A0-3,B0-1 | stage A-low(t+3) | MFMA q(0,0) ----
#pragma unroll
    for (int mf = 0; mf < 4; mf++) aF[mf] = *(const short8*)(buf + aO + mf * 512);
#pragma unroll
    for (int nf = 0; nf < 2; nf++) bF[nf] = *(const short8*)(buf + bO + nf * 512);
    if (doSt) GLDS(ga, dst);
    __builtin_amdgcn_s_barrier();
    __builtin_amdgcn_s_setprio(1);
#pragma unroll
    for (int mf = 0; mf < 4; mf++)
#pragma unroll
      for (int nf = 0; nf < 2; nf++)
        acc[mf][nf] = MFMA_BF16(aF[mf], bF[nf], acc[mf][nf], 0, 0, 0);
    __builtin_amdgcn_s_setprio(0);
    // ---- phase 1: read A4-7 | stage A-high | MFMA q(1,0) ----
#pragma unroll
    for (int mf = 4; mf < 8; mf++) aF[mf] = *(const short8*)(buf + aO + mf * 512);
    if (doSt) GLDS(ga + r128, dst + 4096);
    __builtin_amdgcn_s_barrier();
    __builtin_amdgcn_s_setprio(1);
#pragma unroll
    for (int mf = 4; mf < 8; mf++)
#pragma unroll
      for (int nf = 0; nf < 2; nf++)
        acc[mf][nf] = MFMA_BF16(aF[mf], bF[nf], acc[mf][nf], 0, 0, 0);
    __builtin_amdgcn_s_setprio(0);
    // ---- phase 2: read B2-3 | stage B-low | MFMA q(0,1) ----
#pragma unroll
    for (int nf = 2; nf < 4; nf++) bF[nf] = *(const short8*)(buf + bO + nf * 512);
    if (doSt) GLDS(gb, dst + 8192);
    __builtin_amdgcn_s_barrier();
    __builtin_amdgcn_s_setprio(1);
#pragma unroll
    for (int mf = 0; mf < 4; mf++)
#pragma unroll
      for (int nf = 2; nf < 4; nf++)
        acc[mf][nf] = MFMA_BF16(aF[mf], bF[nf], acc[mf][nf], 0, 0, 0);
    __builtin_amdgcn_s_setprio(0);
    // ---- phase 3: stage B-high | MFMA q(1,1) | counted vmcnt + barrier ----
    if (doSt) GLDS(gb + r128, dst + 12288);
    __builtin_amdgcn_s_barrier();
    __builtin_amdgcn_s_setprio(1);
#pragma unroll
    for (int mf = 4; mf < 8; mf++)
#pragma unroll
      for (int nf = 2; nf < 4; nf++)
        acc[mf][nf] = MFMA_BF16(aF[mf], bF[nf], acc[mf][nf], 0, 0, 0);
    __builtin_amdgcn_s_setprio(0);
    // iter end: guarantee tile t+1 landed; keep tiles t+2,t+3 in flight
    if (t + 4 <= nt)      { WAITVM8; __builtin_amdgcn_s_barrier(); }
    else if (t + 3 == nt) { WAITVM4; __builtin_amdgcn_s_barrier(); }
    else if (t + 2 == nt) { WAITVM0; __builtin_amdgcn_s_barrier(); }
    // t == nt-1: fall through to epilogue
  }
  // epilogue: C row=(lane>>4)*4+j, col=lane&15 (verified layout)
#pragma unroll
  for (int mf = 0; mf < 8; mf++) {
#pragma unroll
    for (int nf = 0; nf < 4; nf++) {
      int col = n0 + wc * 64 + nf * 16 + fr;
      int rowb = m0 + wr * 128 + mf * 16 + fg * 4;
#pragma unroll
      for (int j = 0; j < 4; j++) {
        long long idx = (long long)bz * sC + (long long)(rowb + j) * N + col;
        Cout[idx] = f2bf(acc[mf][nf][j]);
      }
    }
  }
}

// ------- final: row softmax of (dots + c[s]) + blend with l_att -------
__global__ __launch_bounds__(256) void final_kernel(
    const ushort* __restrict__ dots, const float* __restrict__ mask_src,
    const float* __restrict__ steps, const float* __restrict__ mrow,
    const float* __restrict__ zrow, const float* __restrict__ gates,
    const float* __restrict__ c_s, float* __restrict__ out) {
  int row = blockIdx.x;
  int b = row >> 11, t = row & (TL - 1);
  int tid = threadIdx.x;
  int wid = tid >> 6, lane = tid & 63;
  const ushort* dr = dots + (long long)row * SL;
  const float* msk = mask_src + b * SL;
  const float* csb = c_s + b * SL;
  ushort4 u0 = ((const ushort4*)dr)[tid * 2];
  ushort4 u1 = ((const ushort4*)dr)[tid * 2 + 1];
  float4 mk0 = ((const float4*)msk)[tid * 2];
  float4 mk1 = ((const float4*)msk)[tid * 2 + 1];
  float4 cs0 = ((const float4*)csb)[tid * 2];
  float4 cs1 = ((const float4*)csb)[tid * 2 + 1];
  float mk[8] = {mk0.x, mk0.y, mk0.z, mk0.w, mk1.x, mk1.y, mk1.z, mk1.w};
  float cs[8] = {cs0.x, cs0.y, cs0.z, cs0.w, cs1.x, cs1.y, cs1.z, cs1.w};
  float li[8];
  li[0] = bf2f(u0.x); li[1] = bf2f(u0.y); li[2] = bf2f(u0.z); li[3] = bf2f(u0.w);
  li[4] = bf2f(u1.x); li[5] = bf2f(u1.y); li[6] = bf2f(u1.z); li[7] = bf2f(u1.w);
  float lmax = -3e38f;
#pragma unroll
  for (int j = 0; j < 8; j++) {
    li[j] = (li[j] + cs[j] - (1.f - mk[j]) * INF_C) * (1.f / 32.f);
    lmax = fmaxf(lmax, li[j]);
  }
  __shared__ float sm[4], ss[4];
  lmax = wred_max(lmax);
  if (lane == 0) sm[wid] = lmax;
  __syncthreads();
  float m2 = fmaxf(fmaxf(sm[0], sm[1]), fmaxf(sm[2], sm[3]));
  float p[8], lsum = 0.f;
#pragma unroll
  for (int j = 0; j < 8; j++) { p[j] = __expf(li[j] - m2); lsum += p[j]; }
  lsum = wred_sum(lsum);
  if (lane == 0) ss[wid] = lsum;
  __syncthreads();
  float invZ2 = 1.f / (ss[0] + ss[1] + ss[2] + ss[3]);
  float c = steps[b] * (float)t;
  float m1 = mrow[row];
  float invZ1 = 1.f / zrow[row];
  float g = gates[row], omg = 1.f - g;
  float o[8];
#pragma unroll
  for (int j = 0; j < 8; j++) {
    int s = tid * 8 + j;
    float d = (float)s - c;
    float l1 = -d * d * (1.f / 0.3f) - (1.f - mk[j]) * INF_C;
    float la = __expf(l1 - m1) * invZ1;
    o[j] = omg * p[j] * invZ2 + g * la;
  }
  float4* op = (float4*)(out + (long long)row * SL);
  op[tid * 2] = (float4){o[0], o[1], o[2], o[3]};
  op[tid * 2 + 1] = (float4){o[4], o[5], o[6], o[7]};
}

extern "C" void kernel_launch(void* const* d_in, const int* in_sizes, int n_in,
                              void* d_out, int out_size, void* d_ws, size_t ws_size,
                              hipStream_t stream) {
  const float* key      = (const float*)d_in[0];
  const float* mask_src = (const float*)d_in[1];
  const float* mask_trg = (const float*)d_in[2];
  const float* wq_w     = (const float*)d_in[3];
  const float* wq_b     = (const float*)d_in[4];
  const float* wk_w     = (const float*)d_in[5];
  const float* wk_b     = (const float*)d_in[6];   // provably no effect (softmax shift invariance)
  const float* gate_w   = (const float*)d_in[7];
  const float* gate_b   = (const float*)d_in[8];
  float* out = (float*)d_out;
  (void)wk_b;

  // ws layout (elements)
  const long long nKD = (long long)BATCH * SL * DM;  // 16,777,216
  const long long nWW = (long long)DM * DM;          // 1,048,576
  const long long nTS = (long long)BATCH * TL * SL;  // 33,554,432
  ushort* key_bf   = (ushort*)d_ws;
  ushort* query_bf = key_bf + nKD;
  ushort* G_bf     = query_bf + nKD;
  ushort* wqT      = G_bf + nKD;
  ushort* wkT      = wqT + nWW;
  ushort* Wt       = wkT + nWW;
  ushort* dots     = Wt + nWW;
  float*  steps    = (float*)(dots + nTS);
  float*  mrow     = steps + 8;
  float*  zrow     = mrow + BATCH * TL;
  float*  gates    = zrow + BATCH * TL;
  float*  c_s      = gates + BATCH * TL;
  float*  vvec     = c_s + BATCH * SL;
  size_t needed = (size_t)((char*)(vvec + DM) - (char*)d_ws);
  if (ws_size < needed) return;

  // allow 128 KB dynamic LDS (idempotent; harmless if redundant on ROCm)
  hipFuncSetAttribute(reinterpret_cast<const void*>(&gemm256<1>),
                      hipFuncAttributeMaxDynamicSharedMemorySize, 131072);
  hipFuncSetAttribute(reinterpret_cast<const void*>(&gemm256<2>),
                      hipFuncAttributeMaxDynamicSharedMemorySize, 131072);

  steps_kernel<<<BATCH, 256, 0, stream>>>(mask_src, mask_trg, steps);
  hipMemsetAsync(vvec, 0, DM * sizeof(float), stream);
  v_kernel<<<64, 256, 0, stream>>>(wk_w, wq_b, vvec);
  cvt_key_rowc<<<BATCH * SL / 4, 256, 0, stream>>>(key, vvec, key_bf, c_s);
  cvtT<<<dim3(16, 16, 2), 256, 0, stream>>>(wq_w, wk_w, wqT, wkT);
  query_kernel<<<BATCH * TL / 4, 256, 0, stream>>>(key, mask_src, gate_w, gate_b,
                                                   steps, query_bf, mrow, zrow, gates);
  // Wt[l,j] = sum_i wk[i,l]*wq[i,j]  (= W^T, W = wq^T wk)
  gemm_bt<<<dim3(8, 8, 1), 256, 0, stream>>>(wkT, wqT, Wt, DM, DM, DM, 0, 0, 0);
  // G[t,l] = sum_j query[t,j] * Wt[l,j]   [16384,1024]x[1024,1024]
  gemm256<1><<<dim3(4, 64, 1), 512, 131072, stream>>>(
      query_bf, Wt, G_bf, DM, DM, 0, 0, 0);
  // dots[b,t,s] = sum_l G[b,t,l] * key[b,s,l]  per batch [2048,1024]x[2048,1024]^T
  gemm256<2><<<dim3(8, 8, BATCH), 512, 131072, stream>>>(
      G_bf, key_bf, dots, SL, DM,
      (long long)TL * DM, (long long)SL * DM, (long long)TL * SL);
  final_kernel<<<BATCH * TL, 256, 0, stream>>>(dots, mask_src, steps, mrow, zrow,
                                               gates, c_s, out);
}